// Round 2
// 64.583 us; speedup vs baseline: 1.0429x; 1.0429x over previous
//
#include <hip/hip_runtime.h>
#include <math.h>
#include <stdint.h>

// D3PM absorbing q_sample, bit-exact vs JAX threefry PARTITIONABLE mode.
//   split(key):       key_j   = (out0, out1) of threefry(k, hi=0, lo=j)
//   random_bits u32:  bits[i] = out0 ^ out1 of threefry(k, hi32(i), lo32(i))
//
// Only {x0, mask} can win the argmax (floor logit log(1e-10) = -23.03 puts
// all other entries <= -6.39 < min winner -5.17). Per token: 2 threefry
// hashes + a 2-candidate compare.
//
// R5 (re-run; R1 bench was an infra failure): hot path is pure f32 —
// per-b logits via hw v_log_f32, fast gumbel with Taylor-log1p (u>=0.75)
// instead of library log1pf, branchless mask/select per token, ONE
// deferred exact-resolve block per quad (f64 log code inlined 2x total
// instead of 18x). Fast-path total error is bounded by ~4e-5
// (2x gumbel_fast <=4e-6 ea, 2x hw-log logit <=3e-6 ea, f32 rearrangement
// <=~2e-5) << AMB_BAND=2.5e-4, so decisions outside the band provably
// match the reference; inside the band the reference-faithful f64 path
// (identical to verified R3) decides.
//
// Shapes: B=256, L=1024, NS=516 (mask=3), NQ=33 (mask=32).
// Output (int32 flat): noised_structure (B*L), noised_sequence (B*L), t (B).

#define B_CONST 256
#define L_CONST 1024
#define NS_CONST 516
#define NQ_CONST 33
#define MASK_S 3
#define MASK_Q 32
#define ROWS (B_CONST * L_CONST)   /* 262144 */
#define QUADS (ROWS / 4)           /* 65536 token-quads per stream */
#define QUADS_T (B_CONST / 4)      /* 64 */
#define TOTAL_THREADS (2 * QUADS + QUADS_T) /* 131136 */

#define AMB_BAND 2.5e-4f

// ---------------- threefry2x32 (exact JAX schedule) ----------------
__host__ __device__ inline void tf_round(uint32_t& x0, uint32_t& x1, int r) {
  x0 += x1;
  x1 = (x1 << r) | (x1 >> (32 - r));
  x1 ^= x0;
}

__host__ __device__ inline void threefry2x32(uint32_t k0, uint32_t k1,
                                             uint32_t x0, uint32_t x1,
                                             uint32_t& o0, uint32_t& o1) {
  const uint32_t ks2 = k0 ^ k1 ^ 0x1BD11BDAu;
  x0 += k0; x1 += k1;
  tf_round(x0, x1, 13); tf_round(x0, x1, 15); tf_round(x0, x1, 26); tf_round(x0, x1, 6);
  x0 += k1; x1 += ks2 + 1u;
  tf_round(x0, x1, 17); tf_round(x0, x1, 29); tf_round(x0, x1, 16); tf_round(x0, x1, 24);
  x0 += ks2; x1 += k0 + 2u;
  tf_round(x0, x1, 13); tf_round(x0, x1, 15); tf_round(x0, x1, 26); tf_round(x0, x1, 6);
  x0 += k0; x1 += k1 + 3u;
  tf_round(x0, x1, 17); tf_round(x0, x1, 29); tf_round(x0, x1, 16); tf_round(x0, x1, 24);
  x0 += k1; x1 += ks2 + 4u;
  tf_round(x0, x1, 13); tf_round(x0, x1, 15); tf_round(x0, x1, 26); tf_round(x0, x1, 6);
  x0 += ks2; x1 += k0 + 5u;
  o0 = x0; o1 = x1;
}

// ---------------- gumbel paths ----------------
// Exact (reference-faithful): each log correctly rounded to f32 via f64.
// Lives ONLY in the rare ambiguous-resolve block.
__device__ inline float gumbel_exact(uint32_t bits) {
  const float tiny = 1.1754943508222875e-38f;  // jnp.finfo(f32).tiny
  float f = __uint_as_float((bits >> 9) | 0x3f800000u) - 1.0f;
  float u = fmaxf(tiny, f + tiny);
  float nl = -(float)log((double)u);
  return -(float)log((double)nl);
}

__device__ inline float log_cr(float x) { return (float)log((double)x); }

// Fast f32 gumbel, |err| <= ~4e-6 absolute:
//  - u < 0.75:  nl = -__logf(u) >= 0.2877 -> hw log 1-ulp rel, no
//    cancellation possible.
//  - u >= 0.75: t = u-1 in (-0.25, 0], Sterbenz-exact; -log1p(t) via
//    Taylor deg-8: truncation rel err <= |t|^8/9 = 1.7e-6, eval ~1e-6.
//  - outer -__logf(nl): 1 ulp of result, |g| <= 16.6 -> <= 2e-6 abs.
__device__ inline float gumbel_fast(uint32_t bits) {
  const float tiny = 1.1754943508222875e-38f;
  float f = __uint_as_float((bits >> 9) | 0x3f800000u) - 1.0f;
  float u = fmaxf(tiny, f + tiny);
  float t = u - 1.0f;
  float p = -0.125f;                        // -1/8
  p = fmaf(p, t, 1.4285714285714285e-1f);   //  1/7
  p = fmaf(p, t, -1.6666666666666666e-1f);  // -1/6
  p = fmaf(p, t, 2.0e-1f);                  //  1/5
  p = fmaf(p, t, -2.5e-1f);                 // -1/4
  p = fmaf(p, t, 3.3333333333333333e-1f);   //  1/3
  p = fmaf(p, t, -5.0e-1f);                 // -1/2
  p = fmaf(p, t, 1.0f);
  float nl = (u >= 0.75f) ? -(t * p) : -__logf(u);
  return -__logf(nl);
}

// Decide 4 tokens (one int4). Hot path: 8 independent threefry chains +
// 8 fast gumbels, branchless selects, no f64. One deferred exact block
// (reference-faithful f64, first-occurrence argmax tie-break) handles the
// rare |d| <= AMB_BAND tokens.
template <int N, int M>
__device__ inline int4 quad(uint32_t k0, uint32_t k1, uint32_t r0,
                            int4 xs, float a) {
  const float EPSf = 1e-10f;
  const float lxf = __logf(a + EPSf);          // fast logit(x0)
  const float lmf = __logf((1.0f - a) + EPSf); // fast logit(mask)
  const float thr = lmf - lxf;                 // keep x iff gx - gm > thr

  int x[4] = {xs.x, xs.y, xs.z, xs.w};
  uint32_t bx[4], bm[4];
  int res[4];
  int amb = 0;

#pragma unroll
  for (int j = 0; j < 4; ++j) {
    const uint32_t base = (r0 + (uint32_t)j) * (uint32_t)N;
    uint32_t o0, o1;
    threefry2x32(k0, k1, 0u, base + (uint32_t)x[j], o0, o1);
    bx[j] = o0 ^ o1;
    threefry2x32(k0, k1, 0u, base + (uint32_t)M, o0, o1);
    bm[j] = o0 ^ o1;
    const float d = (gumbel_fast(bx[j]) - gumbel_fast(bm[j])) - thr;
    const bool isM = (x[j] == M);   // probs put all mass on mask -> certain
    res[j] = (isM || d <= 0.0f) ? M : x[j];
    if (!isM && fabsf(d) <= AMB_BAND) amb |= (1 << j);
  }

  if (__builtin_expect(amb != 0, 0)) {
    // Reference-faithful resolve: correctly-rounded f32 logits (via f64)
    // and exact gumbels; jnp.argmax first-occurrence tie-break.
    const float lx = log_cr(a + EPSf);
    const float lm = log_cr((1.0f - a) + EPSf);
#pragma unroll
    for (int j = 0; j < 4; ++j) {
      if (amb & (1 << j)) {
        const float vx = gumbel_exact(bx[j]) + lx;
        const float vm = gumbel_exact(bm[j]) + lm;
        if (x[j] < M) res[j] = (vx >= vm) ? x[j] : M;
        else          res[j] = (vm >= vx) ? M : x[j];
      }
    }
  }

  int4 o;
  o.x = res[0]; o.y = res[1]; o.z = res[2]; o.w = res[3];
  return o;
}

__global__ __launch_bounds__(256)
void d3pm_kernel(const int4* __restrict__ structure4,
                 const int4* __restrict__ sequence4,
                 const int* __restrict__ tv,
                 const float* __restrict__ alpha,
                 int4* __restrict__ out4,
                 uint32_t ks0, uint32_t ks1, uint32_t kq0, uint32_t kq1) {
  const int tid = blockIdx.x * 256 + threadIdx.x;

  if (tid < QUADS) {                       // structure: rows 4q..4q+3, same b
    const int q = tid;
    // b = q>>8 is wave-uniform: each 64-lane wave's q-range lies inside one
    // 256-sized b-block (64 | 256) -> force SGPR + scalar loads.
    const int b = __builtin_amdgcn_readfirstlane(q >> 8);
    const float a = alpha[tv[b]];
    out4[q] = quad<NS_CONST, MASK_S>(ks0, ks1, (uint32_t)(4 * q),
                                     structure4[q], a);
  } else if (tid < 2 * QUADS) {            // sequence
    const int q = tid - QUADS;
    const int b = __builtin_amdgcn_readfirstlane(q >> 8);
    const float a = alpha[tv[b]];
    out4[QUADS + q] = quad<NQ_CONST, MASK_Q>(kq0, kq1, (uint32_t)(4 * q),
                                             sequence4[q], a);
  } else if (tid < TOTAL_THREADS) {        // t passthrough
    const int q = tid - 2 * QUADS;
    out4[2 * QUADS + q] = ((const int4*)tv)[q];
  }
}

extern "C" void kernel_launch(void* const* d_in, const int* in_sizes, int n_in,
                              void* d_out, int out_size, void* d_ws, size_t ws_size,
                              hipStream_t stream) {
  (void)in_sizes; (void)n_in; (void)out_size; (void)d_ws; (void)ws_size;
  const int*   structure = (const int*)d_in[0];
  const int*   sequence  = (const int*)d_in[1];
  const int*   t         = (const int*)d_in[2];
  const float* alpha     = (const float*)d_in[3];

  // Partitionable (foldlike) split of key(42) = (0, 42):
  uint32_t ks0, ks1, kq0, kq1;
  threefry2x32(0u, 42u, 0u, 0u, ks0, ks1);
  threefry2x32(0u, 42u, 0u, 1u, kq0, kq1);

  d3pm_kernel<<<(TOTAL_THREADS + 255) / 256, 256, 0, stream>>>(
      (const int4*)structure, (const int4*)sequence, t, alpha,
      (int4*)d_out, ks0, ks1, kq0, kq1);
}